// Round 13
// baseline (448.664 us; speedup 1.0000x reference)
//
#include <hip/hip_runtime.h>
#include <hip/hip_bf16.h>
#include <math.h>

#define NEG_SLOPE 0.2f
typedef __hip_bfloat16 bf16;

__device__ __forceinline__ void edge_sd(const int* __restrict__ ei, int E, int e, int& s, int& d) {
    if (e < E) { s = ei[e]; d = ei[E + e]; }
    else { s = e - E; d = s; }  // self-loop
}

// ================= CSR build =================
__global__ void k_hist(const int* __restrict__ ei, int E, int Etot, int* __restrict__ deg)
{
    int e = blockIdx.x * blockDim.x + threadIdx.x;
    if (e >= Etot) return;
    int s, d; edge_sd(ei, E, e, s, d);
    atomicAdd(&deg[d], 1);
}

__global__ __launch_bounds__(1024) void k_scan(const int* __restrict__ deg,
                                               int* __restrict__ rs, int N)
{
    __shared__ int part[1024];
    int t = threadIdx.x;
    int chunk = (N + 1023) >> 10;
    int b = t * chunk, e = min(b + chunk, N);
    int s = 0;
    for (int i = b; i < e; ++i) s += deg[i];
    part[t] = s;
    __syncthreads();
    for (int off = 1; off < 1024; off <<= 1) {
        int v = (t >= off) ? part[t - off] : 0;
        __syncthreads();
        part[t] += v;
        __syncthreads();
    }
    int excl = (t == 0) ? 0 : part[t - 1];
    for (int i = b; i < e; ++i) { rs[i] = excl; excl += deg[i]; }
    if (t == 1023) rs[N] = part[1023];
}

__global__ void k_fill(const int* __restrict__ ei, int E, int Etot,
                       const int* __restrict__ rs, int* __restrict__ cur,
                       int* __restrict__ csr_src)
{
    int e = blockIdx.x * blockDim.x + threadIdx.x;
    if (e >= Etot) return;
    int s, d; edge_sd(ei, E, e, s, d);
    int pos = rs[d] + atomicAdd(&cur[d], 1);
    csr_src[pos] = s;
}

// ================= Layer 1 =================
// wboth[k][c16]: c<8 -> src-fold head c ; c>=8 -> dst-fold head c-8
__global__ __launch_bounds__(512) void k_prew(
    const float* __restrict__ W1, const float* __restrict__ a_src,
    const float* __restrict__ a_dst, float* __restrict__ wboth)
{
    int t = threadIdx.x;           // 512 = 64 k x 8 h
    int k = t >> 3, h = t & 7;
    float s = 0.f, d = 0.f;
    const float* wr = W1 + k * 512 + h * 64;
    const float* as = a_src + h * 64;
    const float* ad = a_dst + h * 64;
#pragma unroll
    for (int c = 0; c < 64; ++c) { s += wr[c] * as[c]; d += wr[c] * ad[c]; }
    wboth[k * 16 + h] = s;
    wboth[k * 16 + 8 + h] = d;
}

// per-node attention terms: 256 thr = 4 waves x 4 nodes x 16 lanes
__global__ __launch_bounds__(256) void k_alpha1n(
    const float* __restrict__ x, const float* __restrict__ wboth,
    float* __restrict__ asrc, float* __restrict__ adst, int N)
{
    __shared__ float wl[16][64];   // transposed: wl[c][k]
    int t = threadIdx.x;
    for (int i = t; i < 1024; i += 256) {
        int k = i >> 4, c = i & 15;
        wl[c][k] = wboth[i];
    }
    __syncthreads();
    int wave = t >> 6, lane = t & 63;
    int nsub = lane >> 4, ksub = lane & 15;
    int n = blockIdx.x * 16 + wave * 4 + nsub;
    bool valid = (n < N);
    float xv[4];
#pragma unroll
    for (int i = 0; i < 4; ++i)
        xv[i] = valid ? x[(size_t)n * 64 + i * 16 + ksub] : 0.f;
    float acc[16];
#pragma unroll
    for (int c = 0; c < 16; ++c) acc[c] = 0.f;
#pragma unroll
    for (int i = 0; i < 4; ++i) {
        float xi = xv[i];
        int k = i * 16 + ksub;
#pragma unroll
        for (int c = 0; c < 16; ++c) acc[c] += xi * wl[c][k];
    }
#pragma unroll
    for (int c = 0; c < 16; ++c) {
        acc[c] += __shfl_xor(acc[c], 1, 16);
        acc[c] += __shfl_xor(acc[c], 2, 16);
        acc[c] += __shfl_xor(acc[c], 4, 16);
        acc[c] += __shfl_xor(acc[c], 8, 16);
    }
    if (valid) {
        if (ksub < 8) asrc[n * 8 + ksub] = acc[ksub];
        else          adst[n * 8 + (ksub - 8)] = acc[ksub];
    }
}

// softmax layer1: pass A gathers el -> stores into aE + online (m,s);
// pass B reads aE SEQUENTIALLY and overwrites with normalized exp.
// wave per node; lane = (j0 = lane>>3, head h = lane&7)
__global__ __launch_bounds__(256) void k_sm1(
    const int* __restrict__ rs, const int* __restrict__ csr_src,
    const float* __restrict__ asrc, const float* __restrict__ adst,
    float* __restrict__ aE, int N)
{
    int node = blockIdx.x * 4 + (threadIdx.x >> 6);
    if (node >= N) return;
    int lane = threadIdx.x & 63;
    int h = lane & 7, j0 = lane >> 3;
    int base = rs[node], deg = rs[node + 1] - base;
    float ad = adst[node * 8 + h];
    float m = -1e30f, s = 0.f;
    for (int j = j0; j < deg; j += 8) {
        int src = csr_src[base + j];
        float el = asrc[src * 8 + h] + ad;
        el = el >= 0.f ? el : NEG_SLOPE * el;
        aE[(size_t)(base + j) * 8 + h] = el;
        if (el > m) { s = s * __expf(m - el) + 1.f; m = el; }
        else        { s += __expf(el - m); }
    }
#pragma unroll
    for (int off = 8; off < 64; off <<= 1) {
        float m2 = __shfl_xor(m, off, 64);
        float s2 = __shfl_xor(s, off, 64);
        float M = fmaxf(m, m2);
        s = s * __expf(m - M) + s2 * __expf(m2 - M);
        m = M;
    }
    float inv = 1.f / (s + 1e-16f);
    for (int j = j0; j < deg; j += 8) {
        float el = aE[(size_t)(base + j) * 8 + h];
        aE[(size_t)(base + j) * 8 + h] = __expf(el - m) * inv;
    }
}

// ===== fused layer1+layer2-gemm: aggregate + per-head GEMM + ELU + y@W2 + alpha2 dots =====
// phase 1: wave m = node n0+m; lane = k; acc[8] = all heads -> zs (z values).
// phase 2: R11-proven b128 broadcast zs reads, k4 loop NOT unrolled (28 VGPR proven).
// phase 3: y-tile written back into zs (f32); wave w = node w; column-parallel
//   b32 LDS reads (bank = lane%32, 2-way only); width-64 butterfly; h2 + alpha2 dots.
//   part[lane] select done via unrolled cndmask chain (rule #20: no runtime indexing).
// SPILL TRIPWIRE: WRITE_SIZE should be ~4 MB. (full-unroll float4 spills: R5, R8.)
#define NPB 8
__global__ __launch_bounds__(512) void k_agg_gemm1(
    const int* __restrict__ rs, const int* __restrict__ csr_src,
    const float* __restrict__ aE, const float* __restrict__ x,
    const float* __restrict__ W1, const float* __restrict__ b1,
    const float* __restrict__ W2,
    const float* __restrict__ a_src2, const float* __restrict__ a_dst2,
    float* __restrict__ h2, float* __restrict__ asrc2, float* __restrict__ adst2,
    int N)
{
    __shared__ float zs[NPB][512];    // 16 KB: z in phases 1-2, y in phase 3
    __shared__ float W2t[17][512];    // 34.8 KB
    __shared__ float a2s[34];
    int t = threadIdx.x;
    int wave = t >> 6, lane = t & 63;
    int n = blockIdx.x * NPB + wave;

    // stage W2 transposed + alpha2 weights (covered by barrier 1)
    for (int i = t; i < 17 * 512; i += 512) {
        int c = i >> 9, k = i & 511;
        W2t[c][k] = W2[k * 17 + c];
    }
    if (t < 17) a2s[t] = a_src2[t];
    else if (t < 34) a2s[t] = a_dst2[t - 17];

    // ---- phase 1: x-space aggregate ----
    if (n < N) {
        int base = rs[n], deg = rs[n + 1] - base;
        float acc[8];
#pragma unroll
        for (int h = 0; h < 8; ++h) acc[h] = 0.f;
        int j = 0;
        for (; j + 1 < deg; j += 2) {
            int s0 = csr_src[base + j];
            int s1 = csr_src[base + j + 1];
            float xv0 = x[(size_t)s0 * 64 + lane];
            float xv1 = x[(size_t)s1 * 64 + lane];
            const float4* ap0 = (const float4*)(aE + (size_t)(base + j) * 8);
            const float4* ap1 = (const float4*)(aE + (size_t)(base + j + 1) * 8);
            float4 a0 = ap0[0], a1 = ap0[1];
            float4 b0 = ap1[0], b1v = ap1[1];
            acc[0] += a0.x * xv0 + b0.x * xv1;
            acc[1] += a0.y * xv0 + b0.y * xv1;
            acc[2] += a0.z * xv0 + b0.z * xv1;
            acc[3] += a0.w * xv0 + b0.w * xv1;
            acc[4] += a1.x * xv0 + b1v.x * xv1;
            acc[5] += a1.y * xv0 + b1v.y * xv1;
            acc[6] += a1.z * xv0 + b1v.z * xv1;
            acc[7] += a1.w * xv0 + b1v.w * xv1;
        }
        if (j < deg) {
            int s0 = csr_src[base + j];
            float xv0 = x[(size_t)s0 * 64 + lane];
            const float4* ap0 = (const float4*)(aE + (size_t)(base + j) * 8);
            float4 a0 = ap0[0], a1 = ap0[1];
            acc[0] += a0.x * xv0; acc[1] += a0.y * xv0;
            acc[2] += a0.z * xv0; acc[3] += a0.w * xv0;
            acc[4] += a1.x * xv0; acc[5] += a1.y * xv0;
            acc[6] += a1.z * xv0; acc[7] += a1.w * xv0;
        }
#pragma unroll
        for (int h = 0; h < 8; ++h) zs[wave][h * 64 + lane] = acc[h];
    } else {
#pragma unroll
        for (int h = 0; h < 8; ++h) zs[wave][h * 64 + lane] = 0.f;
    }
    __syncthreads();   // (1) z-tile + W2t ready

    // ---- phase 2: per-head GEMM y = z @ W1 (+bias+ELU), y kept in regs ----
    int h = t >> 6;
    float acc2[NPB];
#pragma unroll
    for (int m = 0; m < NPB; ++m) acc2[m] = 0.f;
#pragma unroll 1
    for (int k4 = 0; k4 < 16; ++k4) {
        int k = k4 * 4;
        float w0 = W1[(k + 0) * 512 + t];
        float w1 = W1[(k + 1) * 512 + t];
        float w2 = W1[(k + 2) * 512 + t];
        float w3 = W1[(k + 3) * 512 + t];
#pragma unroll
        for (int m = 0; m < NPB; ++m) {
            float4 zv = *(const float4*)&zs[m][h * 64 + k];
            acc2[m] += zv.x * w0 + zv.y * w1 + zv.z * w2 + zv.w * w3;
        }
    }
    float bias = b1[t];
    __syncthreads();   // (2) all phase-2 zs reads done -> safe to overwrite
#pragma unroll
    for (int m = 0; m < NPB; ++m) {
        float v = acc2[m] + bias;
        v = v > 0.f ? v : __expf(v) - 1.f;
        zs[m][t] = v;   // y-tile, f32; column write: bank = t%32, conflict-free
    }
    __syncthreads();   // (3) y-tile ready

    // ---- phase 3: h2[n] = y[n] @ W2 ; alpha2 dots ----
    int nn3 = blockIdx.x * NPB + wave;
    float y8[8];
#pragma unroll
    for (int j = 0; j < 8; ++j) y8[j] = zs[wave][lane + 64 * j];
    float part[17];
#pragma unroll
    for (int c = 0; c < 17; ++c) {
        float a = 0.f;
#pragma unroll
        for (int j = 0; j < 8; ++j) a += y8[j] * W2t[c][lane + 64 * j];
        part[c] = a;
    }
#pragma unroll
    for (int c = 0; c < 17; ++c) {
#pragma unroll
        for (int off = 1; off < 64; off <<= 1)
            part[c] += __shfl_xor(part[c], off, 64);
    }
    if (nn3 < N) {
        // select part[lane] without runtime indexing (cndmask chain)
        float outv = 0.f;
#pragma unroll
        for (int c = 0; c < 17; ++c) if (lane == c) outv = part[c];
        if (lane < 17) h2[(size_t)nn3 * 17 + lane] = outv;
        if (lane == 20) {
            float s = 0.f;
#pragma unroll
            for (int c = 0; c < 17; ++c) s += part[c] * a2s[c];
            asrc2[nn3] = s;
        }
        if (lane == 21) {
            float d = 0.f;
#pragma unroll
            for (int c = 0; c < 17; ++c) d += part[c] * a2s[17 + c];
            adst2[nn3] = d;
        }
    }
}

// ===== fused layer2 softmax + aggregate + bias + log_softmax =====
// wave per node. pass A: all 64 lanes online (m,s) over edges.
// pass B: lane = (jsub = lane>>5, c = lane&31); alpha recomputed inline.
__global__ __launch_bounds__(256) void k_out(
    const int* __restrict__ rs, const int* __restrict__ csr_src,
    const float* __restrict__ asrc, const float* __restrict__ adst,
    const float* __restrict__ h2,
    const float* __restrict__ b2, float* __restrict__ out, int N)
{
    int node = blockIdx.x * 4 + (threadIdx.x >> 6);
    if (node >= N) return;
    int lane = threadIdx.x & 63;
    int base = rs[node], deg = rs[node + 1] - base;
    float ad = adst[node];

    // pass A: online (m,s)
    float m = -1e30f, s = 0.f;
    for (int j = lane; j < deg; j += 64) {
        float el = asrc[csr_src[base + j]] + ad;
        el = el >= 0.f ? el : NEG_SLOPE * el;
        if (el > m) { s = s * __expf(m - el) + 1.f; m = el; }
        else        { s += __expf(el - m); }
    }
#pragma unroll
    for (int off = 1; off < 64; off <<= 1) {
        float m2 = __shfl_xor(m, off, 64);
        float s2 = __shfl_xor(s, off, 64);
        float M = fmaxf(m, m2);
        s = s * __expf(m - M) + s2 * __expf(m2 - M);
        m = M;
    }
    float inv = 1.f / (s + 1e-16f);

    // pass B: aggregate with inline alpha
    int c = lane & 31, jsub = lane >> 5;
    float acc = 0.f;
    if (c < 17) {
        for (int p = base + jsub; p < base + deg; p += 2) {
            int src = csr_src[p];
            float el = asrc[src] + ad;
            el = el >= 0.f ? el : NEG_SLOPE * el;
            float alpha = __expf(el - m) * inv;
            acc += alpha * h2[(size_t)src * 17 + c];
        }
    }
    acc += __shfl_xor(acc, 32, 64);  // combine the two edge halves
    float logit = (c < 17) ? acc + b2[c] : -1e30f;
    float mm = logit;
#pragma unroll
    for (int off = 1; off < 32; off <<= 1) mm = fmaxf(mm, __shfl_xor(mm, off, 32));
    float p = (c < 17) ? __expf(logit - mm) : 0.f;
    float ssum = p;
#pragma unroll
    for (int off = 1; off < 32; off <<= 1) ssum += __shfl_xor(ssum, off, 32);
    if (c < 17 && jsub == 0) out[(size_t)node * 17 + c] = logit - mm - logf(ssum);
}

extern "C" void kernel_launch(void* const* d_in, const int* in_sizes, int n_in,
                              void* d_out, int out_size, void* d_ws, size_t ws_size,
                              hipStream_t stream)
{
    const float* x      = (const float*)d_in[0];
    const int*   ei     = (const int*)d_in[1];
    const float* W1     = (const float*)d_in[2];
    const float* asrc1w = (const float*)d_in[3];
    const float* adst1w = (const float*)d_in[4];
    const float* b1     = (const float*)d_in[5];
    const float* W2     = (const float*)d_in[6];
    const float* asrc2w = (const float*)d_in[7];
    const float* adst2w = (const float*)d_in[8];
    const float* b2     = (const float*)d_in[9];
    float* out = (float*)d_out;

    const int N = in_sizes[0] / 64;
    const int E = in_sizes[1] / 2;
    const int Etot = N + E;

    // workspace layout
    float* ws = (float*)d_ws;
    size_t o = 0;
    float* wboth  = ws + o; o += 1024;
    float* asrc1  = ws + o; o += (size_t)N * 8;
    float* adst1  = ws + o; o += (size_t)N * 8;
    float* aE1    = ws + o; o += (size_t)Etot * 8;
    float* h2     = ws + o; o += (size_t)N * 17;
    float* asrc2  = ws + o; o += (size_t)N;
    float* adst2  = ws + o; o += (size_t)N;
    int* deg      = (int*)(ws + o); o += (size_t)N;
    int* cur      = (int*)(ws + o); o += (size_t)N;
    int* rs       = (int*)(ws + o); o += (size_t)N + 1;
    int* csr_src  = (int*)(ws + o); o += (size_t)Etot;

    hipMemsetAsync(deg, 0, (size_t)N * 4, stream);
    hipMemsetAsync(cur, 0, (size_t)N * 4, stream);

    // CSR build
    {
        int blk = 256, g = (Etot + blk - 1) / blk;
        k_hist<<<g, blk, 0, stream>>>(ei, E, Etot, deg);
        k_scan<<<1, 1024, 0, stream>>>(deg, rs, N);
        k_fill<<<g, blk, 0, stream>>>(ei, E, Etot, rs, cur, csr_src);
    }

    // layer 1
    k_prew<<<1, 512, 0, stream>>>(W1, asrc1w, adst1w, wboth);
    k_alpha1n<<<(N + 15) / 16, 256, 0, stream>>>(x, wboth, asrc1, adst1, N);
    k_sm1<<<(N + 3) / 4, 256, 0, stream>>>(rs, csr_src, asrc1, adst1, aE1, N);
    k_agg_gemm1<<<(N + NPB - 1) / NPB, 512, 0, stream>>>(
        rs, csr_src, aE1, x, W1, b1, W2, asrc2w, adst2w, h2, asrc2, adst2, N);

    // layer 2 output
    k_out<<<(N + 3) / 4, 256, 0, stream>>>(rs, csr_src, asrc2, adst2, h2, b2, out, N);
}

// Round 14
// 370.790 us; speedup vs baseline: 1.2100x; 1.2100x over previous
//
#include <hip/hip_runtime.h>
#include <hip/hip_bf16.h>
#include <hip/hip_fp16.h>
#include <math.h>

#define NEG_SLOPE 0.2f
typedef __hip_bfloat16 bf16;
typedef __attribute__((ext_vector_type(8))) unsigned short ushort8;
typedef _Float16 f16x2 __attribute__((ext_vector_type(2)));

// XOR swizzle: logical float-column c -> physical column (breaks stride-32 conflicts)
#define SWZ(c) ((c) ^ ((((c) >> 5) & 7) << 2))

__device__ __forceinline__ float bf2f(unsigned short u) {
    return __uint_as_float(((unsigned)u) << 16);
}

#if __has_builtin(__builtin_amdgcn_fdot2)
__device__ __forceinline__ float fdot2u(unsigned zu, unsigned wu, float acc) {
    return __builtin_amdgcn_fdot2(__builtin_bit_cast(f16x2, zu),
                                  __builtin_bit_cast(f16x2, wu), acc, false);
}
#else
__device__ __forceinline__ float fdot2u(unsigned zu, unsigned wu, float acc) {
    f16x2 z = __builtin_bit_cast(f16x2, zu);
    f16x2 w = __builtin_bit_cast(f16x2, wu);
    return acc + (float)z[0] * (float)w[0] + (float)z[1] * (float)w[1];
}
#endif

__device__ __forceinline__ void edge_sd(const int* __restrict__ ei, int E, int e, int& s, int& d) {
    if (e < E) { s = ei[e]; d = ei[E + e]; }
    else { s = e - E; d = s; }  // self-loop
}

// ================= CSR build =================
__global__ void k_hist(const int* __restrict__ ei, int E, int Etot, int* __restrict__ deg)
{
    int e = blockIdx.x * blockDim.x + threadIdx.x;
    if (e >= Etot) return;
    int s, d; edge_sd(ei, E, e, s, d);
    atomicAdd(&deg[d], 1);
}

__global__ __launch_bounds__(1024) void k_scan(const int* __restrict__ deg,
                                               int* __restrict__ rs, int N)
{
    __shared__ int part[1024];
    int t = threadIdx.x;
    int chunk = (N + 1023) >> 10;
    int b = t * chunk, e = min(b + chunk, N);
    int s = 0;
    for (int i = b; i < e; ++i) s += deg[i];
    part[t] = s;
    __syncthreads();
    for (int off = 1; off < 1024; off <<= 1) {
        int v = (t >= off) ? part[t - off] : 0;
        __syncthreads();
        part[t] += v;
        __syncthreads();
    }
    int excl = (t == 0) ? 0 : part[t - 1];
    for (int i = b; i < e; ++i) { rs[i] = excl; excl += deg[i]; }
    if (t == 1023) rs[N] = part[1023];
}

__global__ void k_fill(const int* __restrict__ ei, int E, int Etot,
                       const int* __restrict__ rs, int* __restrict__ cur,
                       int* __restrict__ csr_src)
{
    int e = blockIdx.x * blockDim.x + threadIdx.x;
    if (e >= Etot) return;
    int s, d; edge_sd(ei, E, e, s, d);
    int pos = rs[d] + atomicAdd(&cur[d], 1);
    csr_src[pos] = s;
}

// ================= Layer 1 =================
// wboth[k][c16]: c<8 -> src-fold head c ; c>=8 -> dst-fold head c-8
__global__ __launch_bounds__(512) void k_prew(
    const float* __restrict__ W1, const float* __restrict__ a_src,
    const float* __restrict__ a_dst, float* __restrict__ wboth)
{
    int t = threadIdx.x;           // 512 = 64 k x 8 h
    int k = t >> 3, h = t & 7;
    float s = 0.f, d = 0.f;
    const float* wr = W1 + k * 512 + h * 64;
    const float* as = a_src + h * 64;
    const float* ad = a_dst + h * 64;
#pragma unroll
    for (int c = 0; c < 64; ++c) { s += wr[c] * as[c]; d += wr[c] * ad[c]; }
    wboth[k * 16 + h] = s;
    wboth[k * 16 + 8 + h] = d;
}

// pack W1 into half2 k-pairs: W1q[kb*2048 + t*4 + q] = half2(W1[kb*8+2q][t], W1[kb*8+2q+1][t])
__global__ void k_packw1(const float* __restrict__ W1, unsigned* __restrict__ W1q)
{
    int i = blockIdx.x * blockDim.x + threadIdx.x;
    if (i >= 8 * 512 * 4) return;
    int q = i & 3, t = (i >> 2) & 511, kb = i >> 11;
    int r0 = kb * 8 + 2 * q;
    __half lo = __float2half(W1[r0 * 512 + t]);
    __half hi = __float2half(W1[(r0 + 1) * 512 + t]);
    W1q[i] = (unsigned)__half_as_ushort(lo) | ((unsigned)__half_as_ushort(hi) << 16);
}

// per-node attention terms: 256 thr = 4 waves x 4 nodes x 16 lanes
__global__ __launch_bounds__(256) void k_alpha1n(
    const float* __restrict__ x, const float* __restrict__ wboth,
    float* __restrict__ asrc, float* __restrict__ adst, int N)
{
    __shared__ float wl[16][64];   // transposed: wl[c][k]
    int t = threadIdx.x;
    for (int i = t; i < 1024; i += 256) {
        int k = i >> 4, c = i & 15;
        wl[c][k] = wboth[i];
    }
    __syncthreads();
    int wave = t >> 6, lane = t & 63;
    int nsub = lane >> 4, ksub = lane & 15;
    int n = blockIdx.x * 16 + wave * 4 + nsub;
    bool valid = (n < N);
    float xv[4];
#pragma unroll
    for (int i = 0; i < 4; ++i)
        xv[i] = valid ? x[(size_t)n * 64 + i * 16 + ksub] : 0.f;
    float acc[16];
#pragma unroll
    for (int c = 0; c < 16; ++c) acc[c] = 0.f;
#pragma unroll
    for (int i = 0; i < 4; ++i) {
        float xi = xv[i];
        int k = i * 16 + ksub;
#pragma unroll
        for (int c = 0; c < 16; ++c) acc[c] += xi * wl[c][k];
    }
#pragma unroll
    for (int c = 0; c < 16; ++c) {
        acc[c] += __shfl_xor(acc[c], 1, 16);
        acc[c] += __shfl_xor(acc[c], 2, 16);
        acc[c] += __shfl_xor(acc[c], 4, 16);
        acc[c] += __shfl_xor(acc[c], 8, 16);
    }
    if (valid) {
        if (ksub < 8) asrc[n * 8 + ksub] = acc[ksub];
        else          adst[n * 8 + (ksub - 8)] = acc[ksub];
    }
}

// softmax layer1: pass A gathers el -> stores into aE + online (m,s);
// pass B reads aE SEQUENTIALLY and overwrites with normalized exp.
__global__ __launch_bounds__(256) void k_sm1(
    const int* __restrict__ rs, const int* __restrict__ csr_src,
    const float* __restrict__ asrc, const float* __restrict__ adst,
    float* __restrict__ aE, int N)
{
    int node = blockIdx.x * 4 + (threadIdx.x >> 6);
    if (node >= N) return;
    int lane = threadIdx.x & 63;
    int h = lane & 7, j0 = lane >> 3;
    int base = rs[node], deg = rs[node + 1] - base;
    float ad = adst[node * 8 + h];
    float m = -1e30f, s = 0.f;
    for (int j = j0; j < deg; j += 8) {
        int src = csr_src[base + j];
        float el = asrc[src * 8 + h] + ad;
        el = el >= 0.f ? el : NEG_SLOPE * el;
        aE[(size_t)(base + j) * 8 + h] = el;
        if (el > m) { s = s * __expf(m - el) + 1.f; m = el; }
        else        { s += __expf(el - m); }
    }
#pragma unroll
    for (int off = 8; off < 64; off <<= 1) {
        float m2 = __shfl_xor(m, off, 64);
        float s2 = __shfl_xor(s, off, 64);
        float M = fmaxf(m, m2);
        s = s * __expf(m - M) + s2 * __expf(m2 - M);
        m = M;
    }
    float inv = 1.f / (s + 1e-16f);
    for (int j = j0; j < deg; j += 8) {
        float el = aE[(size_t)(base + j) * 8 + h];
        aE[(size_t)(base + j) * 8 + h] = __expf(el - m) * inv;
    }
}

// ===== fused: x-space aggregate (wave per node) + per-head GEMM + bias + ELU =====
// phase 1: R12-proven gather (28 VGPR); z stored to LDS as f16 (8 KB).
// phase 2: b128 brings 8 k-values (f16); v_dot2_f32_f16 pairs vs pre-packed W1q.
//   64 ds_read_b128/thread (was 128) + 256 dot2 (was 512 FMA). kb loop unroll 1.
// SPILL TRIPWIRE: WRITE_SIZE ~50 MB. (full-unroll variants spill: R5, R8.)
#define NPB 8
__global__ __launch_bounds__(512) void k_agg_gemm1(
    const int* __restrict__ rs, const int* __restrict__ csr_src,
    const float* __restrict__ aE, const float* __restrict__ x,
    const unsigned* __restrict__ W1q, const float* __restrict__ b1,
    bf16* __restrict__ y, int N)
{
    __shared__ unsigned short zsh[NPB][512];   // 8 KB, f16 bits; [m][h*64+k]
    int t = threadIdx.x;
    int wave = t >> 6, lane = t & 63;
    int n = blockIdx.x * NPB + wave;

    if (n < N) {
        int base = rs[n], deg = rs[n + 1] - base;
        float acc[8];
#pragma unroll
        for (int h = 0; h < 8; ++h) acc[h] = 0.f;
        int j = 0;
        for (; j + 1 < deg; j += 2) {
            int s0 = csr_src[base + j];
            int s1 = csr_src[base + j + 1];
            float xv0 = x[(size_t)s0 * 64 + lane];
            float xv1 = x[(size_t)s1 * 64 + lane];
            const float4* ap0 = (const float4*)(aE + (size_t)(base + j) * 8);
            const float4* ap1 = (const float4*)(aE + (size_t)(base + j + 1) * 8);
            float4 a0 = ap0[0], a1 = ap0[1];
            float4 b0 = ap1[0], b1v = ap1[1];
            acc[0] += a0.x * xv0 + b0.x * xv1;
            acc[1] += a0.y * xv0 + b0.y * xv1;
            acc[2] += a0.z * xv0 + b0.z * xv1;
            acc[3] += a0.w * xv0 + b0.w * xv1;
            acc[4] += a1.x * xv0 + b1v.x * xv1;
            acc[5] += a1.y * xv0 + b1v.y * xv1;
            acc[6] += a1.z * xv0 + b1v.z * xv1;
            acc[7] += a1.w * xv0 + b1v.w * xv1;
        }
        if (j < deg) {
            int s0 = csr_src[base + j];
            float xv0 = x[(size_t)s0 * 64 + lane];
            const float4* ap0 = (const float4*)(aE + (size_t)(base + j) * 8);
            float4 a0 = ap0[0], a1 = ap0[1];
            acc[0] += a0.x * xv0; acc[1] += a0.y * xv0;
            acc[2] += a0.z * xv0; acc[3] += a0.w * xv0;
            acc[4] += a1.x * xv0; acc[5] += a1.y * xv0;
            acc[6] += a1.z * xv0; acc[7] += a1.w * xv0;
        }
#pragma unroll
        for (int h = 0; h < 8; ++h)
            zsh[wave][h * 64 + lane] = __half_as_ushort(__float2half(acc[h]));
    } else {
#pragma unroll
        for (int h = 0; h < 8; ++h) zsh[wave][h * 64 + lane] = 0;
    }
    __syncthreads();

    // phase 2: y[n0+m][t] = elu( dot_f16(z[m][h*64..], W1[..][t]) + b1[t] ), h = t>>6
    int n0 = blockIdx.x * NPB;
    int h = t >> 6;
    float acc2[NPB];
#pragma unroll
    for (int m = 0; m < NPB; ++m) acc2[m] = 0.f;
#pragma unroll 1
    for (int kb = 0; kb < 8; ++kb) {
        uint4 w4 = *(const uint4*)(W1q + kb * 2048 + t * 4);
#pragma unroll
        for (int m = 0; m < NPB; ++m) {
            uint4 z4 = *(const uint4*)&zsh[m][h * 64 + kb * 8];  // 8 halves, broadcast
            float a = acc2[m];
            a = fdot2u(z4.x, w4.x, a);
            a = fdot2u(z4.y, w4.y, a);
            a = fdot2u(z4.z, w4.z, a);
            a = fdot2u(z4.w, w4.w, a);
            acc2[m] = a;
        }
    }
    float bias = b1[t];
#pragma unroll
    for (int m = 0; m < NPB; ++m) {
        int nn = n0 + m;
        if (nn < N) {
            float v = acc2[m] + bias;
            v = v > 0.f ? v : __expf(v) - 1.f;
            y[(size_t)nn * 512 + t] = __float2bfloat16(v);
        }
    }
}

// ================= Layer 2 =================
// h2 = y @ W2 (+ fused attention dots). 512 thr = 8 waves x 4 nodes x 16 lanes.
__global__ __launch_bounds__(512) void k_gemm2(
    const bf16* __restrict__ y, const float* __restrict__ W2,
    const float* __restrict__ a_src2, const float* __restrict__ a_dst2,
    float* __restrict__ h2, float* __restrict__ asrc, float* __restrict__ adst, int N)
{
    __shared__ float W2t[17][512];
    __shared__ float a2s[34];
    int t = threadIdx.x;
    for (int i = t; i < 17 * 512; i += 512) {
        int c = i >> 9, k = i & 511;
        W2t[c][SWZ(k)] = W2[k * 17 + c];
    }
    if (t < 17) a2s[t] = a_src2[t];
    else if (t < 34) a2s[t] = a_dst2[t - 17];
    __syncthreads();

    int wave = t >> 6, lane = t & 63;
    int nsub = lane >> 4, ksub = lane & 15;
    int kx = ksub & 7;

#pragma unroll
    for (int pass = 0; pass < 2; ++pass) {
        int n = blockIdx.x * 64 + pass * 32 + wave * 4 + nsub;
        bool valid = (n < N);

        float yk[32];
        if (valid) {
            const ushort8* yr = (const ushort8*)(y + (size_t)n * 512 + ksub * 32);
#pragma unroll
            for (int v = 0; v < 4; ++v) {
                ushort8 u = yr[v];
#pragma unroll
                for (int j = 0; j < 8; ++j) yk[v * 8 + j] = bf2f(u[j]);
            }
        } else {
#pragma unroll
            for (int i = 0; i < 32; ++i) yk[i] = 0.f;
        }

        float acc[17];
#pragma unroll
        for (int c = 0; c < 17; ++c) {
            float a = 0.f;
#pragma unroll
            for (int v = 0; v < 8; ++v) {
                const float4 w = *(const float4*)&W2t[c][ksub * 32 + ((v ^ kx) << 2)];
                a += yk[v * 4 + 0] * w.x + yk[v * 4 + 1] * w.y
                   + yk[v * 4 + 2] * w.z + yk[v * 4 + 3] * w.w;
            }
            acc[c] = a;
        }
#pragma unroll
        for (int c = 0; c < 17; ++c) {
            acc[c] += __shfl_xor(acc[c], 1, 16);
            acc[c] += __shfl_xor(acc[c], 2, 16);
            acc[c] += __shfl_xor(acc[c], 4, 16);
            acc[c] += __shfl_xor(acc[c], 8, 16);
        }
        if (valid) {
            if (ksub < 16) h2[(size_t)n * 17 + ksub] = acc[ksub];
            if (ksub == 0) h2[(size_t)n * 17 + 16] = acc[16];
            if (ksub == 1) {
                float s = 0.f;
#pragma unroll
                for (int c = 0; c < 17; ++c) s += acc[c] * a2s[c];
                asrc[n] = s;
            }
            if (ksub == 2) {
                float d = 0.f;
#pragma unroll
                for (int c = 0; c < 17; ++c) d += acc[c] * a2s[17 + c];
                adst[n] = d;
            }
        }
    }
}

// ===== fused layer2 softmax + aggregate + bias + log_softmax =====
__global__ __launch_bounds__(256) void k_out(
    const int* __restrict__ rs, const int* __restrict__ csr_src,
    const float* __restrict__ asrc, const float* __restrict__ adst,
    const float* __restrict__ h2,
    const float* __restrict__ b2, float* __restrict__ out, int N)
{
    int node = blockIdx.x * 4 + (threadIdx.x >> 6);
    if (node >= N) return;
    int lane = threadIdx.x & 63;
    int base = rs[node], deg = rs[node + 1] - base;
    float ad = adst[node];

    float m = -1e30f, s = 0.f;
    for (int j = lane; j < deg; j += 64) {
        float el = asrc[csr_src[base + j]] + ad;
        el = el >= 0.f ? el : NEG_SLOPE * el;
        if (el > m) { s = s * __expf(m - el) + 1.f; m = el; }
        else        { s += __expf(el - m); }
    }
#pragma unroll
    for (int off = 1; off < 64; off <<= 1) {
        float m2 = __shfl_xor(m, off, 64);
        float s2 = __shfl_xor(s, off, 64);
        float M = fmaxf(m, m2);
        s = s * __expf(m - M) + s2 * __expf(m2 - M);
        m = M;
    }
    float inv = 1.f / (s + 1e-16f);

    int c = lane & 31, jsub = lane >> 5;
    float acc = 0.f;
    if (c < 17) {
        for (int p = base + jsub; p < base + deg; p += 2) {
            int src = csr_src[p];
            float el = asrc[src] + ad;
            el = el >= 0.f ? el : NEG_SLOPE * el;
            float alpha = __expf(el - m) * inv;
            acc += alpha * h2[(size_t)src * 17 + c];
        }
    }
    acc += __shfl_xor(acc, 32, 64);
    float logit = (c < 17) ? acc + b2[c] : -1e30f;
    float mm = logit;
#pragma unroll
    for (int off = 1; off < 32; off <<= 1) mm = fmaxf(mm, __shfl_xor(mm, off, 32));
    float p = (c < 17) ? __expf(logit - mm) : 0.f;
    float ssum = p;
#pragma unroll
    for (int off = 1; off < 32; off <<= 1) ssum += __shfl_xor(ssum, off, 32);
    if (c < 17 && jsub == 0) out[(size_t)node * 17 + c] = logit - mm - logf(ssum);
}

extern "C" void kernel_launch(void* const* d_in, const int* in_sizes, int n_in,
                              void* d_out, int out_size, void* d_ws, size_t ws_size,
                              hipStream_t stream)
{
    const float* x      = (const float*)d_in[0];
    const int*   ei     = (const int*)d_in[1];
    const float* W1     = (const float*)d_in[2];
    const float* asrc1w = (const float*)d_in[3];
    const float* adst1w = (const float*)d_in[4];
    const float* b1     = (const float*)d_in[5];
    const float* W2     = (const float*)d_in[6];
    const float* asrc2w = (const float*)d_in[7];
    const float* adst2w = (const float*)d_in[8];
    const float* b2     = (const float*)d_in[9];
    float* out = (float*)d_out;

    const int N = in_sizes[0] / 64;
    const int E = in_sizes[1] / 2;
    const int Etot = N + E;

    // workspace layout
    float* ws = (float*)d_ws;
    size_t o = 0;
    bf16*  y      = (bf16*)(ws + o); o += (size_t)N * 256;   // N*512 bf16
    float* wboth  = ws + o; o += 1024;
    unsigned* W1q = (unsigned*)(ws + o); o += 8 * 512 * 4;   // 16384 uints
    float* asrc1  = ws + o; o += (size_t)N * 8;
    float* adst1  = ws + o; o += (size_t)N * 8;
    float* aE1    = ws + o; o += (size_t)Etot * 8;
    float* h2     = ws + o; o += (size_t)N * 17;
    float* asrc2  = ws + o; o += (size_t)N;
    float* adst2  = ws + o; o += (size_t)N;
    int* deg      = (int*)(ws + o); o += (size_t)N;
    int* cur      = (int*)(ws + o); o += (size_t)N;
    int* rs       = (int*)(ws + o); o += (size_t)N + 1;
    int* csr_src  = (int*)(ws + o); o += (size_t)Etot;

    hipMemsetAsync(deg, 0, (size_t)N * 4, stream);
    hipMemsetAsync(cur, 0, (size_t)N * 4, stream);

    // CSR build
    {
        int blk = 256, g = (Etot + blk - 1) / blk;
        k_hist<<<g, blk, 0, stream>>>(ei, E, Etot, deg);
        k_scan<<<1, 1024, 0, stream>>>(deg, rs, N);
        k_fill<<<g, blk, 0, stream>>>(ei, E, Etot, rs, cur, csr_src);
    }

    // layer 1
    k_prew<<<1, 512, 0, stream>>>(W1, asrc1w, adst1w, wboth);
    k_packw1<<<64, 256, 0, stream>>>(W1, W1q);
    k_alpha1n<<<(N + 15) / 16, 256, 0, stream>>>(x, wboth, asrc1, adst1, N);
    k_sm1<<<(N + 3) / 4, 256, 0, stream>>>(rs, csr_src, asrc1, adst1, aE1, N);
    k_agg_gemm1<<<(N + NPB - 1) / NPB, 512, 0, stream>>>(rs, csr_src, aE1, x, W1q, b1, y, N);

    // layer 2
    k_gemm2<<<(N + 63) / 64, 512, 0, stream>>>(y, W2, asrc2w, adst2w, h2, asrc2, adst2, N);
    k_out<<<(N + 3) / 4, 256, 0, stream>>>(rs, csr_src, asrc2, adst2, h2, b2, out, N);
}

// Round 15
// 358.286 us; speedup vs baseline: 1.2522x; 1.0349x over previous
//
#include <hip/hip_runtime.h>
#include <hip/hip_bf16.h>
#include <hip/hip_fp16.h>
#include <math.h>

#define NEG_SLOPE 0.2f
typedef __hip_bfloat16 bf16;
typedef __attribute__((ext_vector_type(8))) unsigned short ushort8;
typedef _Float16 f16x8 __attribute__((ext_vector_type(8)));
typedef float f32x4 __attribute__((ext_vector_type(4)));

// XOR swizzle for W2t in gemm2 (breaks stride-32 conflicts)
#define SWZ(c) ((c) ^ ((((c) >> 5) & 7) << 2))

__device__ __forceinline__ float bf2f(unsigned short u) {
    return __uint_as_float(((unsigned)u) << 16);
}

__device__ __forceinline__ void edge_sd(const int* __restrict__ ei, int E, int e, int& s, int& d) {
    if (e < E) { s = ei[e]; d = ei[E + e]; }
    else { s = e - E; d = s; }  // self-loop
}

// ================= CSR build =================
__global__ void k_hist(const int* __restrict__ ei, int E, int Etot, int* __restrict__ deg)
{
    int e = blockIdx.x * blockDim.x + threadIdx.x;
    if (e >= Etot) return;
    int s, d; edge_sd(ei, E, e, s, d);
    atomicAdd(&deg[d], 1);
}

__global__ __launch_bounds__(1024) void k_scan(const int* __restrict__ deg,
                                               int* __restrict__ rs, int N)
{
    __shared__ int part[1024];
    int t = threadIdx.x;
    int chunk = (N + 1023) >> 10;
    int b = t * chunk, e = min(b + chunk, N);
    int s = 0;
    for (int i = b; i < e; ++i) s += deg[i];
    part[t] = s;
    __syncthreads();
    for (int off = 1; off < 1024; off <<= 1) {
        int v = (t >= off) ? part[t - off] : 0;
        __syncthreads();
        part[t] += v;
        __syncthreads();
    }
    int excl = (t == 0) ? 0 : part[t - 1];
    for (int i = b; i < e; ++i) { rs[i] = excl; excl += deg[i]; }
    if (t == 1023) rs[N] = part[1023];
}

__global__ void k_fill(const int* __restrict__ ei, int E, int Etot,
                       const int* __restrict__ rs, int* __restrict__ cur,
                       int* __restrict__ csr_src)
{
    int e = blockIdx.x * blockDim.x + threadIdx.x;
    if (e >= Etot) return;
    int s, d; edge_sd(ei, E, e, s, d);
    int pos = rs[d] + atomicAdd(&cur[d], 1);
    csr_src[pos] = s;
}

// ================= Layer 1 =================
// wboth[k][c16]: c<8 -> src-fold head c ; c>=8 -> dst-fold head c-8
__global__ __launch_bounds__(512) void k_prew(
    const float* __restrict__ W1, const float* __restrict__ a_src,
    const float* __restrict__ a_dst, float* __restrict__ wboth)
{
    int t = threadIdx.x;           // 512 = 64 k x 8 h
    int k = t >> 3, h = t & 7;
    float s = 0.f, d = 0.f;
    const float* wr = W1 + k * 512 + h * 64;
    const float* as = a_src + h * 64;
    const float* ad = a_dst + h * 64;
#pragma unroll
    for (int c = 0; c < 64; ++c) { s += wr[c] * as[c]; d += wr[c] * ad[c]; }
    wboth[k * 16 + h] = s;
    wboth[k * 16 + 8 + h] = d;
}

// pack W1 into MFMA B-fragment order (f16).
// tile = ((h*2+ks)<<2)|nt ; lane l: col = h*64+nt*16+(l&15), k = ks*32+(l>>4)*8+j
__global__ void k_packw1f(const float* __restrict__ W1, unsigned short* __restrict__ W1f)
{
    int i = blockIdx.x * blockDim.x + threadIdx.x;
    if (i >= 64 * 512) return;
    int tile = i >> 9;
    int rem = i & 511;
    int l = rem >> 3, j = rem & 7;
    int h = tile >> 3, ks = (tile >> 2) & 1, nt = tile & 3;
    int k = ks * 32 + (l >> 4) * 8 + j;
    int col = h * 64 + nt * 16 + (l & 15);
    W1f[i] = __half_as_ushort(__float2half(W1[k * 512 + col]));
}

// per-node attention terms: 256 thr = 4 waves x 4 nodes x 16 lanes
__global__ __launch_bounds__(256) void k_alpha1n(
    const float* __restrict__ x, const float* __restrict__ wboth,
    float* __restrict__ asrc, float* __restrict__ adst, int N)
{
    __shared__ float wl[16][64];   // transposed: wl[c][k]
    int t = threadIdx.x;
    for (int i = t; i < 1024; i += 256) {
        int k = i >> 4, c = i & 15;
        wl[c][k] = wboth[i];
    }
    __syncthreads();
    int wave = t >> 6, lane = t & 63;
    int nsub = lane >> 4, ksub = lane & 15;
    int n = blockIdx.x * 16 + wave * 4 + nsub;
    bool valid = (n < N);
    float xv[4];
#pragma unroll
    for (int i = 0; i < 4; ++i)
        xv[i] = valid ? x[(size_t)n * 64 + i * 16 + ksub] : 0.f;
    float acc[16];
#pragma unroll
    for (int c = 0; c < 16; ++c) acc[c] = 0.f;
#pragma unroll
    for (int i = 0; i < 4; ++i) {
        float xi = xv[i];
        int k = i * 16 + ksub;
#pragma unroll
        for (int c = 0; c < 16; ++c) acc[c] += xi * wl[c][k];
    }
#pragma unroll
    for (int c = 0; c < 16; ++c) {
        acc[c] += __shfl_xor(acc[c], 1, 16);
        acc[c] += __shfl_xor(acc[c], 2, 16);
        acc[c] += __shfl_xor(acc[c], 4, 16);
        acc[c] += __shfl_xor(acc[c], 8, 16);
    }
    if (valid) {
        if (ksub < 8) asrc[n * 8 + ksub] = acc[ksub];
        else          adst[n * 8 + (ksub - 8)] = acc[ksub];
    }
}

// softmax layer1: pass A gathers el -> stores into aE + online (m,s);
// pass B reads aE SEQUENTIALLY and overwrites with normalized exp.
__global__ __launch_bounds__(256) void k_sm1(
    const int* __restrict__ rs, const int* __restrict__ csr_src,
    const float* __restrict__ asrc, const float* __restrict__ adst,
    float* __restrict__ aE, int N)
{
    int node = blockIdx.x * 4 + (threadIdx.x >> 6);
    if (node >= N) return;
    int lane = threadIdx.x & 63;
    int h = lane & 7, j0 = lane >> 3;
    int base = rs[node], deg = rs[node + 1] - base;
    float ad = adst[node * 8 + h];
    float m = -1e30f, s = 0.f;
    for (int j = j0; j < deg; j += 8) {
        int src = csr_src[base + j];
        float el = asrc[src * 8 + h] + ad;
        el = el >= 0.f ? el : NEG_SLOPE * el;
        aE[(size_t)(base + j) * 8 + h] = el;
        if (el > m) { s = s * __expf(m - el) + 1.f; m = el; }
        else        { s += __expf(el - m); }
    }
#pragma unroll
    for (int off = 8; off < 64; off <<= 1) {
        float m2 = __shfl_xor(m, off, 64);
        float s2 = __shfl_xor(s, off, 64);
        float M = fmaxf(m, m2);
        s = s * __expf(m - M) + s2 * __expf(m2 - M);
        m = M;
    }
    float inv = 1.f / (s + 1e-16f);
    for (int j = j0; j < deg; j += 8) {
        float el = aE[(size_t)(base + j) * 8 + h];
        aE[(size_t)(base + j) * 8 + h] = __expf(el - m) * inv;
    }
}

// ===== fused: x-space aggregate + MFMA per-head GEMM + bias + ELU =====
// NPB=16 nodes/block, 512 thr = 8 waves.
// phase 1: wave w gathers nodes n0+w and n0+w+8 (R12-proven gather shape);
//   z stored f16 into XOR-swizzled LDS rows (byte ^= (row&7)<<4; write & read
//   use the SAME xor — both-sides rule).
// phase 2: wave = head h. 8x mfma_f32_16x16x32_f16 (4 N-tiles x 2 K-halves).
//   A-frag: row=l&15, k=(l>>4)*8+j  (1 ds_read_b128/lane per K-half)
//   B-frag: prepacked W1f, 16B/lane coalesced global (L2-hot)
//   C/D: col=lane&15, row=(lane>>4)*4+reg (m89-verified, dtype-independent)
// SPILL TRIPWIRE: WRITE_SIZE ~50 MB. (full-unroll float4 spills: R5, R8.)
#define NPB 16
__global__ __launch_bounds__(512) void k_agg_gemm1(
    const int* __restrict__ rs, const int* __restrict__ csr_src,
    const float* __restrict__ aE, const float* __restrict__ x,
    const unsigned short* __restrict__ W1f, const float* __restrict__ b1,
    bf16* __restrict__ y, int N)
{
    __shared__ __align__(16) unsigned short zsh[16 * 512];   // 16 KB f16, swizzled
    int t = threadIdx.x;
    int wave = t >> 6, lane = t & 63;
    int n0 = blockIdx.x * NPB;

    // ---- phase 1: gather 2 nodes per wave ----
#pragma unroll 1
    for (int half = 0; half < 2; ++half) {
        int r = wave + half * 8;
        int n = n0 + r;
        float acc[8];
#pragma unroll
        for (int h = 0; h < 8; ++h) acc[h] = 0.f;
        if (n < N) {
            int base = rs[n], deg = rs[n + 1] - base;
            int j = 0;
            for (; j + 1 < deg; j += 2) {
                int s0 = csr_src[base + j];
                int s1 = csr_src[base + j + 1];
                float xv0 = x[(size_t)s0 * 64 + lane];
                float xv1 = x[(size_t)s1 * 64 + lane];
                const float4* ap0 = (const float4*)(aE + (size_t)(base + j) * 8);
                const float4* ap1 = (const float4*)(aE + (size_t)(base + j + 1) * 8);
                float4 a0 = ap0[0], a1 = ap0[1];
                float4 b0 = ap1[0], b1v = ap1[1];
                acc[0] += a0.x * xv0 + b0.x * xv1;
                acc[1] += a0.y * xv0 + b0.y * xv1;
                acc[2] += a0.z * xv0 + b0.z * xv1;
                acc[3] += a0.w * xv0 + b0.w * xv1;
                acc[4] += a1.x * xv0 + b1v.x * xv1;
                acc[5] += a1.y * xv0 + b1v.y * xv1;
                acc[6] += a1.z * xv0 + b1v.z * xv1;
                acc[7] += a1.w * xv0 + b1v.w * xv1;
            }
            if (j < deg) {
                int s0 = csr_src[base + j];
                float xv0 = x[(size_t)s0 * 64 + lane];
                const float4* ap0 = (const float4*)(aE + (size_t)(base + j) * 8);
                float4 a0 = ap0[0], a1 = ap0[1];
                acc[0] += a0.x * xv0; acc[1] += a0.y * xv0;
                acc[2] += a0.z * xv0; acc[3] += a0.w * xv0;
                acc[4] += a1.x * xv0; acc[5] += a1.y * xv0;
                acc[6] += a1.z * xv0; acc[7] += a1.w * xv0;
            }
        }
        unsigned xr = (unsigned)((r & 7) << 4);
#pragma unroll
        for (int h = 0; h < 8; ++h) {
            unsigned byte = ((unsigned)(r * 1024 + h * 128 + lane * 2)) ^ xr;
            *(unsigned short*)((char*)zsh + byte) =
                __half_as_ushort(__float2half(acc[h]));
        }
    }
    __syncthreads();

    // ---- phase 2: y[n0+row][h*64+nt*16+col] via MFMA ----
    {
        int h = wave;
        int rA = lane & 15, q = lane >> 4;
        f32x4 acc[4] = {{0.f,0.f,0.f,0.f},{0.f,0.f,0.f,0.f},
                        {0.f,0.f,0.f,0.f},{0.f,0.f,0.f,0.f}};
        const uint4* W1f4 = (const uint4*)W1f;
#pragma unroll
        for (int ks = 0; ks < 2; ++ks) {
            unsigned byte = ((unsigned)(rA * 1024 + h * 128 + ks * 64 + q * 16))
                            ^ ((unsigned)((rA & 7) << 4));
            uint4 au = *(const uint4*)((const char*)zsh + byte);
            f16x8 a = __builtin_bit_cast(f16x8, au);
#pragma unroll
            for (int nt = 0; nt < 4; ++nt) {
                int tile = ((h * 2 + ks) << 2) | nt;
                f16x8 b = __builtin_bit_cast(f16x8, W1f4[tile * 64 + lane]);
                acc[nt] = __builtin_amdgcn_mfma_f32_16x16x32_f16(a, b, acc[nt], 0, 0, 0);
            }
        }
        int cl = lane & 15, qr = lane >> 4;
#pragma unroll
        for (int nt = 0; nt < 4; ++nt) {
            int colo = h * 64 + nt * 16 + cl;
            float bias = b1[colo];
#pragma unroll
            for (int j = 0; j < 4; ++j) {
                int row = qr * 4 + j;
                int nn = n0 + row;
                if (nn < N) {
                    float v = acc[nt][j] + bias;
                    v = v > 0.f ? v : __expf(v) - 1.f;
                    y[(size_t)nn * 512 + colo] = __float2bfloat16(v);
                }
            }
        }
    }
}

// ================= Layer 2 =================
// h2 = y @ W2 (+ fused attention dots). 512 thr = 8 waves x 4 nodes x 16 lanes.
__global__ __launch_bounds__(512) void k_gemm2(
    const bf16* __restrict__ y, const float* __restrict__ W2,
    const float* __restrict__ a_src2, const float* __restrict__ a_dst2,
    float* __restrict__ h2, float* __restrict__ asrc, float* __restrict__ adst, int N)
{
    __shared__ float W2t[17][512];
    __shared__ float a2s[34];
    int t = threadIdx.x;
    for (int i = t; i < 17 * 512; i += 512) {
        int c = i >> 9, k = i & 511;
        W2t[c][SWZ(k)] = W2[k * 17 + c];
    }
    if (t < 17) a2s[t] = a_src2[t];
    else if (t < 34) a2s[t] = a_dst2[t - 17];
    __syncthreads();

    int wave = t >> 6, lane = t & 63;
    int nsub = lane >> 4, ksub = lane & 15;
    int kx = ksub & 7;

#pragma unroll
    for (int pass = 0; pass < 2; ++pass) {
        int n = blockIdx.x * 64 + pass * 32 + wave * 4 + nsub;
        bool valid = (n < N);

        float yk[32];
        if (valid) {
            const ushort8* yr = (const ushort8*)(y + (size_t)n * 512 + ksub * 32);
#pragma unroll
            for (int v = 0; v < 4; ++v) {
                ushort8 u = yr[v];
#pragma unroll
                for (int j = 0; j < 8; ++j) yk[v * 8 + j] = bf2f(u[j]);
            }
        } else {
#pragma unroll
            for (int i = 0; i < 32; ++i) yk[i] = 0.f;
        }

        float acc[17];
#pragma unroll
        for (int c = 0; c < 17; ++c) {
            float a = 0.f;
#pragma unroll
            for (int v = 0; v < 8; ++v) {
                const float4 w = *(const float4*)&W2t[c][ksub * 32 + ((v ^ kx) << 2)];
                a += yk[v * 4 + 0] * w.x + yk[v * 4 + 1] * w.y
                   + yk[v * 4 + 2] * w.z + yk[v * 4 + 3] * w.w;
            }
            acc[c] = a;
        }
#pragma unroll
        for (int c = 0; c < 17; ++c) {
            acc[c] += __shfl_xor(acc[c], 1, 16);
            acc[c] += __shfl_xor(acc[c], 2, 16);
            acc[c] += __shfl_xor(acc[c], 4, 16);
            acc[c] += __shfl_xor(acc[c], 8, 16);
        }
        if (valid) {
            if (ksub < 16) h2[(size_t)n * 17 + ksub] = acc[ksub];
            if (ksub == 0) h2[(size_t)n * 17 + 16] = acc[16];
            if (ksub == 1) {
                float s = 0.f;
#pragma unroll
                for (int c = 0; c < 17; ++c) s += acc[c] * a2s[c];
                asrc[n] = s;
            }
            if (ksub == 2) {
                float d = 0.f;
#pragma unroll
                for (int c = 0; c < 17; ++c) d += acc[c] * a2s[17 + c];
                adst[n] = d;
            }
        }
    }
}

// ===== fused layer2 softmax + aggregate + bias + log_softmax =====
__global__ __launch_bounds__(256) void k_out(
    const int* __restrict__ rs, const int* __restrict__ csr_src,
    const float* __restrict__ asrc, const float* __restrict__ adst,
    const float* __restrict__ h2,
    const float* __restrict__ b2, float* __restrict__ out, int N)
{
    int node = blockIdx.x * 4 + (threadIdx.x >> 6);
    if (node >= N) return;
    int lane = threadIdx.x & 63;
    int base = rs[node], deg = rs[node + 1] - base;
    float ad = adst[node];

    float m = -1e30f, s = 0.f;
    for (int j = lane; j < deg; j += 64) {
        float el = asrc[csr_src[base + j]] + ad;
        el = el >= 0.f ? el : NEG_SLOPE * el;
        if (el > m) { s = s * __expf(m - el) + 1.f; m = el; }
        else        { s += __expf(el - m); }
    }
#pragma unroll
    for (int off = 1; off < 64; off <<= 1) {
        float m2 = __shfl_xor(m, off, 64);
        float s2 = __shfl_xor(s, off, 64);
        float M = fmaxf(m, m2);
        s = s * __expf(m - M) + s2 * __expf(m2 - M);
        m = M;
    }
    float inv = 1.f / (s + 1e-16f);

    int c = lane & 31, jsub = lane >> 5;
    float acc = 0.f;
    if (c < 17) {
        for (int p = base + jsub; p < base + deg; p += 2) {
            int src = csr_src[p];
            float el = asrc[src] + ad;
            el = el >= 0.f ? el : NEG_SLOPE * el;
            float alpha = __expf(el - m) * inv;
            acc += alpha * h2[(size_t)src * 17 + c];
        }
    }
    acc += __shfl_xor(acc, 32, 64);
    float logit = (c < 17) ? acc + b2[c] : -1e30f;
    float mm = logit;
#pragma unroll
    for (int off = 1; off < 32; off <<= 1) mm = fmaxf(mm, __shfl_xor(mm, off, 32));
    float p = (c < 17) ? __expf(logit - mm) : 0.f;
    float ssum = p;
#pragma unroll
    for (int off = 1; off < 32; off <<= 1) ssum += __shfl_xor(ssum, off, 32);
    if (c < 17 && jsub == 0) out[(size_t)node * 17 + c] = logit - mm - logf(ssum);
}

extern "C" void kernel_launch(void* const* d_in, const int* in_sizes, int n_in,
                              void* d_out, int out_size, void* d_ws, size_t ws_size,
                              hipStream_t stream)
{
    const float* x      = (const float*)d_in[0];
    const int*   ei     = (const int*)d_in[1];
    const float* W1     = (const float*)d_in[2];
    const float* asrc1w = (const float*)d_in[3];
    const float* adst1w = (const float*)d_in[4];
    const float* b1     = (const float*)d_in[5];
    const float* W2     = (const float*)d_in[6];
    const float* asrc2w = (const float*)d_in[7];
    const float* adst2w = (const float*)d_in[8];
    const float* b2     = (const float*)d_in[9];
    float* out = (float*)d_out;

    const int N = in_sizes[0] / 64;
    const int E = in_sizes[1] / 2;
    const int Etot = N + E;

    // workspace layout
    float* ws = (float*)d_ws;
    size_t o = 0;
    bf16*  y      = (bf16*)(ws + o); o += (size_t)N * 256;   // N*512 bf16
    float* wboth  = ws + o; o += 1024;
    unsigned short* W1f = (unsigned short*)(ws + o); o += 64 * 512 / 2;  // 32768 halves
    float* asrc1  = ws + o; o += (size_t)N * 8;
    float* adst1  = ws + o; o += (size_t)N * 8;
    float* aE1    = ws + o; o += (size_t)Etot * 8;
    float* h2     = ws + o; o += (size_t)N * 17;
    float* asrc2  = ws + o; o += (size_t)N;
    float* adst2  = ws + o; o += (size_t)N;
    int* deg      = (int*)(ws + o); o += (size_t)N;
    int* cur      = (int*)(ws + o); o += (size_t)N;
    int* rs       = (int*)(ws + o); o += (size_t)N + 1;
    int* csr_src  = (int*)(ws + o); o += (size_t)Etot;

    hipMemsetAsync(deg, 0, (size_t)N * 4, stream);
    hipMemsetAsync(cur, 0, (size_t)N * 4, stream);

    // CSR build
    {
        int blk = 256, g = (Etot + blk - 1) / blk;
        k_hist<<<g, blk, 0, stream>>>(ei, E, Etot, deg);
        k_scan<<<1, 1024, 0, stream>>>(deg, rs, N);
        k_fill<<<g, blk, 0, stream>>>(ei, E, Etot, rs, cur, csr_src);
    }

    // layer 1
    k_prew<<<1, 512, 0, stream>>>(W1, asrc1w, adst1w, wboth);
    k_packw1f<<<128, 256, 0, stream>>>(W1, W1f);
    k_alpha1n<<<(N + 15) / 16, 256, 0, stream>>>(x, wboth, asrc1, adst1, N);
    k_sm1<<<(N + 3) / 4, 256, 0, stream>>>(rs, csr_src, asrc1, adst1, aE1, N);
    k_agg_gemm1<<<(N + NPB - 1) / NPB, 512, 0, stream>>>(rs, csr_src, aE1, x, W1f, b1, y, N);

    // layer 2
    k_gemm2<<<(N + 63) / 64, 512, 0, stream>>>(y, W2, asrc2w, adst2w, h2, asrc2, adst2, N);
    k_out<<<(N + 3) / 4, 256, 0, stream>>>(rs, csr_src, asrc2, adst2, h2, b2, out, N);
}

// Round 16
// 318.011 us; speedup vs baseline: 1.4108x; 1.1266x over previous
//
#include <hip/hip_runtime.h>
#include <hip/hip_bf16.h>
#include <hip/hip_fp16.h>
#include <math.h>

#define NEG_SLOPE 0.2f
typedef __hip_bfloat16 bf16;
typedef __attribute__((ext_vector_type(8))) unsigned short ushort8;
typedef _Float16 f16x8 __attribute__((ext_vector_type(8)));
typedef __attribute__((ext_vector_type(8))) short s16x8;
typedef float f32x4 __attribute__((ext_vector_type(4)));

__device__ __forceinline__ float bf2f(unsigned short u) {
    return __uint_as_float(((unsigned)u) << 16);
}
__device__ __forceinline__ unsigned short f2bf_bits(float v) {
    return (unsigned short)(__float_as_uint(__bfloat162float(__float2bfloat16(v))) >> 16);
}

__device__ __forceinline__ void edge_sd(const int* __restrict__ ei, int E, int e, int& s, int& d) {
    if (e < E) { s = ei[e]; d = ei[E + e]; }
    else { s = e - E; d = s; }  // self-loop
}

// ================= CSR build =================
__global__ void k_hist(const int* __restrict__ ei, int E, int Etot, int* __restrict__ deg)
{
    int e = blockIdx.x * blockDim.x + threadIdx.x;
    if (e >= Etot) return;
    int s, d; edge_sd(ei, E, e, s, d);
    atomicAdd(&deg[d], 1);
}

__global__ __launch_bounds__(1024) void k_scan(const int* __restrict__ deg,
                                               int* __restrict__ rs, int N)
{
    __shared__ int part[1024];
    int t = threadIdx.x;
    int chunk = (N + 1023) >> 10;
    int b = t * chunk, e = min(b + chunk, N);
    int s = 0;
    for (int i = b; i < e; ++i) s += deg[i];
    part[t] = s;
    __syncthreads();
    for (int off = 1; off < 1024; off <<= 1) {
        int v = (t >= off) ? part[t - off] : 0;
        __syncthreads();
        part[t] += v;
        __syncthreads();
    }
    int excl = (t == 0) ? 0 : part[t - 1];
    for (int i = b; i < e; ++i) { rs[i] = excl; excl += deg[i]; }
    if (t == 1023) rs[N] = part[1023];
}

__global__ void k_fill(const int* __restrict__ ei, int E, int Etot,
                       const int* __restrict__ rs, int* __restrict__ cur,
                       int* __restrict__ csr_src)
{
    int e = blockIdx.x * blockDim.x + threadIdx.x;
    if (e >= Etot) return;
    int s, d; edge_sd(ei, E, e, s, d);
    int pos = rs[d] + atomicAdd(&cur[d], 1);
    csr_src[pos] = s;
}

// ================= Layer 1 =================
// wboth[k][c16]: c<8 -> src-fold head c ; c>=8 -> dst-fold head c-8
__global__ __launch_bounds__(512) void k_prew(
    const float* __restrict__ W1, const float* __restrict__ a_src,
    const float* __restrict__ a_dst, float* __restrict__ wboth)
{
    int t = threadIdx.x;           // 512 = 64 k x 8 h
    int k = t >> 3, h = t & 7;
    float s = 0.f, d = 0.f;
    const float* wr = W1 + k * 512 + h * 64;
    const float* as = a_src + h * 64;
    const float* ad = a_dst + h * 64;
#pragma unroll
    for (int c = 0; c < 64; ++c) { s += wr[c] * as[c]; d += wr[c] * ad[c]; }
    wboth[k * 16 + h] = s;
    wboth[k * 16 + 8 + h] = d;
}

// pack W1 into MFMA B-fragment order (f16).
// tile = ((h*2+ks)<<2)|nt ; lane l: col = h*64+nt*16+(l&15), k = ks*32+(l>>4)*8+j
__global__ void k_packw1f(const float* __restrict__ W1, unsigned short* __restrict__ W1f)
{
    int i = blockIdx.x * blockDim.x + threadIdx.x;
    if (i >= 64 * 512) return;
    int tile = i >> 9;
    int rem = i & 511;
    int l = rem >> 3, j = rem & 7;
    int h = tile >> 3, ks = (tile >> 2) & 1, nt = tile & 3;
    int k = ks * 32 + (l >> 4) * 8 + j;
    int col = h * 64 + nt * 16 + (l & 15);
    W1f[i] = __half_as_ushort(__float2half(W1[k * 512 + col]));
}

// pack extended W2 into MFMA B-fragment order (bf16).
// extended cols: 0-16 = W2, 17 = W2@a_src2, 18 = W2@a_dst2, 19-31 = 0.
// tile = ks*2+nt ; lane l: col = nt*16+(l&15), k = ks*32+(l>>4)*8+j
__global__ void k_packw2(const float* __restrict__ W2,
                         const float* __restrict__ a_src2, const float* __restrict__ a_dst2,
                         unsigned short* __restrict__ W2f)
{
    int i = blockIdx.x * blockDim.x + threadIdx.x;
    if (i >= 32 * 512) return;
    int tile = i >> 9;
    int rem = i & 511;
    int l = rem >> 3, j = rem & 7;
    int ks = tile >> 1, nt = tile & 1;
    int k = ks * 32 + (l >> 4) * 8 + j;
    int col = nt * 16 + (l & 15);
    float v = 0.f;
    if (col < 17) v = W2[k * 17 + col];
    else if (col == 17) { for (int c = 0; c < 17; ++c) v += W2[k * 17 + c] * a_src2[c]; }
    else if (col == 18) { for (int c = 0; c < 17; ++c) v += W2[k * 17 + c] * a_dst2[c]; }
    W2f[i] = f2bf_bits(v);
}

// per-node attention terms: 256 thr = 4 waves x 4 nodes x 16 lanes
__global__ __launch_bounds__(256) void k_alpha1n(
    const float* __restrict__ x, const float* __restrict__ wboth,
    float* __restrict__ asrc, float* __restrict__ adst, int N)
{
    __shared__ float wl[16][64];   // transposed: wl[c][k]
    int t = threadIdx.x;
    for (int i = t; i < 1024; i += 256) {
        int k = i >> 4, c = i & 15;
        wl[c][k] = wboth[i];
    }
    __syncthreads();
    int wave = t >> 6, lane = t & 63;
    int nsub = lane >> 4, ksub = lane & 15;
    int n = blockIdx.x * 16 + wave * 4 + nsub;
    bool valid = (n < N);
    float xv[4];
#pragma unroll
    for (int i = 0; i < 4; ++i)
        xv[i] = valid ? x[(size_t)n * 64 + i * 16 + ksub] : 0.f;
    float acc[16];
#pragma unroll
    for (int c = 0; c < 16; ++c) acc[c] = 0.f;
#pragma unroll
    for (int i = 0; i < 4; ++i) {
        float xi = xv[i];
        int k = i * 16 + ksub;
#pragma unroll
        for (int c = 0; c < 16; ++c) acc[c] += xi * wl[c][k];
    }
#pragma unroll
    for (int c = 0; c < 16; ++c) {
        acc[c] += __shfl_xor(acc[c], 1, 16);
        acc[c] += __shfl_xor(acc[c], 2, 16);
        acc[c] += __shfl_xor(acc[c], 4, 16);
        acc[c] += __shfl_xor(acc[c], 8, 16);
    }
    if (valid) {
        if (ksub < 8) asrc[n * 8 + ksub] = acc[ksub];
        else          adst[n * 8 + (ksub - 8)] = acc[ksub];
    }
}

// softmax layer1: pass A gathers el -> stores into aE + online (m,s);
// pass B reads aE SEQUENTIALLY and overwrites with normalized exp.
__global__ __launch_bounds__(256) void k_sm1(
    const int* __restrict__ rs, const int* __restrict__ csr_src,
    const float* __restrict__ asrc, const float* __restrict__ adst,
    float* __restrict__ aE, int N)
{
    int node = blockIdx.x * 4 + (threadIdx.x >> 6);
    if (node >= N) return;
    int lane = threadIdx.x & 63;
    int h = lane & 7, j0 = lane >> 3;
    int base = rs[node], deg = rs[node + 1] - base;
    float ad = adst[node * 8 + h];
    float m = -1e30f, s = 0.f;
    for (int j = j0; j < deg; j += 8) {
        int src = csr_src[base + j];
        float el = asrc[src * 8 + h] + ad;
        el = el >= 0.f ? el : NEG_SLOPE * el;
        aE[(size_t)(base + j) * 8 + h] = el;
        if (el > m) { s = s * __expf(m - el) + 1.f; m = el; }
        else        { s += __expf(el - m); }
    }
#pragma unroll
    for (int off = 8; off < 64; off <<= 1) {
        float m2 = __shfl_xor(m, off, 64);
        float s2 = __shfl_xor(s, off, 64);
        float M = fmaxf(m, m2);
        s = s * __expf(m - M) + s2 * __expf(m2 - M);
        m = M;
    }
    float inv = 1.f / (s + 1e-16f);
    for (int j = j0; j < deg; j += 8) {
        float el = aE[(size_t)(base + j) * 8 + h];
        aE[(size_t)(base + j) * 8 + h] = __expf(el - m) * inv;
    }
}

// ===== fused: x-space aggregate + MFMA per-head GEMM + bias + ELU (R15-proven) =====
#define NPB 16
__global__ __launch_bounds__(512) void k_agg_gemm1(
    const int* __restrict__ rs, const int* __restrict__ csr_src,
    const float* __restrict__ aE, const float* __restrict__ x,
    const unsigned short* __restrict__ W1f, const float* __restrict__ b1,
    bf16* __restrict__ y, int N)
{
    __shared__ __align__(16) unsigned short zsh[16 * 512];   // 16 KB f16, swizzled
    int t = threadIdx.x;
    int wave = t >> 6, lane = t & 63;
    int n0 = blockIdx.x * NPB;

    // ---- phase 1: gather 2 nodes per wave ----
#pragma unroll 1
    for (int half = 0; half < 2; ++half) {
        int r = wave + half * 8;
        int n = n0 + r;
        float acc[8];
#pragma unroll
        for (int h = 0; h < 8; ++h) acc[h] = 0.f;
        if (n < N) {
            int base = rs[n], deg = rs[n + 1] - base;
            int j = 0;
            for (; j + 1 < deg; j += 2) {
                int s0 = csr_src[base + j];
                int s1 = csr_src[base + j + 1];
                float xv0 = x[(size_t)s0 * 64 + lane];
                float xv1 = x[(size_t)s1 * 64 + lane];
                const float4* ap0 = (const float4*)(aE + (size_t)(base + j) * 8);
                const float4* ap1 = (const float4*)(aE + (size_t)(base + j + 1) * 8);
                float4 a0 = ap0[0], a1 = ap0[1];
                float4 b0 = ap1[0], b1v = ap1[1];
                acc[0] += a0.x * xv0 + b0.x * xv1;
                acc[1] += a0.y * xv0 + b0.y * xv1;
                acc[2] += a0.z * xv0 + b0.z * xv1;
                acc[3] += a0.w * xv0 + b0.w * xv1;
                acc[4] += a1.x * xv0 + b1v.x * xv1;
                acc[5] += a1.y * xv0 + b1v.y * xv1;
                acc[6] += a1.z * xv0 + b1v.z * xv1;
                acc[7] += a1.w * xv0 + b1v.w * xv1;
            }
            if (j < deg) {
                int s0 = csr_src[base + j];
                float xv0 = x[(size_t)s0 * 64 + lane];
                const float4* ap0 = (const float4*)(aE + (size_t)(base + j) * 8);
                float4 a0 = ap0[0], a1 = ap0[1];
                acc[0] += a0.x * xv0; acc[1] += a0.y * xv0;
                acc[2] += a0.z * xv0; acc[3] += a0.w * xv0;
                acc[4] += a1.x * xv0; acc[5] += a1.y * xv0;
                acc[6] += a1.z * xv0; acc[7] += a1.w * xv0;
            }
        }
        unsigned xr = (unsigned)((r & 7) << 4);
#pragma unroll
        for (int h = 0; h < 8; ++h) {
            unsigned byte = ((unsigned)(r * 1024 + h * 128 + lane * 2)) ^ xr;
            *(unsigned short*)((char*)zsh + byte) =
                __half_as_ushort(__float2half(acc[h]));
        }
    }
    __syncthreads();

    // ---- phase 2: y[n0+row][h*64+nt*16+col] via MFMA ----
    {
        int h = wave;
        int rA = lane & 15, q = lane >> 4;
        f32x4 acc[4] = {{0.f,0.f,0.f,0.f},{0.f,0.f,0.f,0.f},
                        {0.f,0.f,0.f,0.f},{0.f,0.f,0.f,0.f}};
        const uint4* W1f4 = (const uint4*)W1f;
#pragma unroll
        for (int ks = 0; ks < 2; ++ks) {
            unsigned byte = ((unsigned)(rA * 1024 + h * 128 + ks * 64 + q * 16))
                            ^ ((unsigned)((rA & 7) << 4));
            uint4 au = *(const uint4*)((const char*)zsh + byte);
            f16x8 a = __builtin_bit_cast(f16x8, au);
#pragma unroll
            for (int nt = 0; nt < 4; ++nt) {
                int tile = ((h * 2 + ks) << 2) | nt;
                f16x8 b = __builtin_bit_cast(f16x8, W1f4[tile * 64 + lane]);
                acc[nt] = __builtin_amdgcn_mfma_f32_16x16x32_f16(a, b, acc[nt], 0, 0, 0);
            }
        }
        int cl = lane & 15, qr = lane >> 4;
#pragma unroll
        for (int nt = 0; nt < 4; ++nt) {
            int colo = h * 64 + nt * 16 + cl;
            float bias = b1[colo];
#pragma unroll
            for (int j = 0; j < 4; ++j) {
                int row = qr * 4 + j;
                int nn = n0 + row;
                if (nn < N) {
                    float v = acc[nt][j] + bias;
                    v = v > 0.f ? v : __expf(v) - 1.f;
                    y[(size_t)nn * 512 + colo] = __float2bfloat16(v);
                }
            }
        }
    }
}

// ================= Layer 2: MFMA gemm2, no LDS =================
// wave = 16 nodes; A = y rows (bf16, 16B/lane); B = prepacked extended W2 (L2 broadcast).
// Extended cols: 0-16 = h2, 17 = asrc2, 18 = adst2 (alpha dots folded into B).
// A-frag: row=l&15, k=(l>>4)*8+j ; C/D: col=l&15, row=(l>>4)*4+reg (R15-verified).
__global__ __launch_bounds__(512) void k_gemm2(
    const bf16* __restrict__ y, const unsigned short* __restrict__ W2f,
    float* __restrict__ h2, float* __restrict__ asrc, float* __restrict__ adst, int N)
{
    int t = threadIdx.x;
    int wave = t >> 6, lane = t & 63;
    int n0 = blockIdx.x * 128 + wave * 16;
    int rA = lane & 15, q = lane >> 4;
    f32x4 acc0 = {0.f,0.f,0.f,0.f}, acc1 = {0.f,0.f,0.f,0.f};
    const uint4* W2f4 = (const uint4*)W2f;
    const bf16* yrow = y + (size_t)(n0 + rA) * 512;
#pragma unroll 1
    for (int ks = 0; ks < 16; ++ks) {
        uint4 au = *(const uint4*)(yrow + ks * 32 + q * 8);
        s16x8 a = __builtin_bit_cast(s16x8, au);
        s16x8 b0 = __builtin_bit_cast(s16x8, W2f4[(ks * 2 + 0) * 64 + lane]);
        s16x8 b1 = __builtin_bit_cast(s16x8, W2f4[(ks * 2 + 1) * 64 + lane]);
        acc0 = __builtin_amdgcn_mfma_f32_16x16x32_bf16(a, b0, acc0, 0, 0, 0);
        acc1 = __builtin_amdgcn_mfma_f32_16x16x32_bf16(a, b1, acc1, 0, 0, 0);
    }
    int cl = lane & 15, qr = lane >> 4;
#pragma unroll
    for (int j = 0; j < 4; ++j) {
        int n = n0 + qr * 4 + j;
        if (n < N) {
            h2[(size_t)n * 17 + cl] = acc0[j];
            if (cl == 0) h2[(size_t)n * 17 + 16] = acc1[j];
            if (cl == 1) asrc[n] = acc1[j];
            if (cl == 2) adst[n] = acc1[j];
        }
    }
}

// ===== fused layer2 softmax + aggregate + bias + log_softmax =====
__global__ __launch_bounds__(256) void k_out(
    const int* __restrict__ rs, const int* __restrict__ csr_src,
    const float* __restrict__ asrc, const float* __restrict__ adst,
    const float* __restrict__ h2,
    const float* __restrict__ b2, float* __restrict__ out, int N)
{
    int node = blockIdx.x * 4 + (threadIdx.x >> 6);
    if (node >= N) return;
    int lane = threadIdx.x & 63;
    int base = rs[node], deg = rs[node + 1] - base;
    float ad = adst[node];

    float m = -1e30f, s = 0.f;
    for (int j = lane; j < deg; j += 64) {
        float el = asrc[csr_src[base + j]] + ad;
        el = el >= 0.f ? el : NEG_SLOPE * el;
        if (el > m) { s = s * __expf(m - el) + 1.f; m = el; }
        else        { s += __expf(el - m); }
    }
#pragma unroll
    for (int off = 1; off < 64; off <<= 1) {
        float m2 = __shfl_xor(m, off, 64);
        float s2 = __shfl_xor(s, off, 64);
        float M = fmaxf(m, m2);
        s = s * __expf(m - M) + s2 * __expf(m2 - M);
        m = M;
    }
    float inv = 1.f / (s + 1e-16f);

    int c = lane & 31, jsub = lane >> 5;
    float acc = 0.f;
    if (c < 17) {
        for (int p = base + jsub; p < base + deg; p += 2) {
            int src = csr_src[p];
            float el = asrc[src] + ad;
            el = el >= 0.f ? el : NEG_SLOPE * el;
            float alpha = __expf(el - m) * inv;
            acc += alpha * h2[(size_t)src * 17 + c];
        }
    }
    acc += __shfl_xor(acc, 32, 64);
    float logit = (c < 17) ? acc + b2[c] : -1e30f;
    float mm = logit;
#pragma unroll
    for (int off = 1; off < 32; off <<= 1) mm = fmaxf(mm, __shfl_xor(mm, off, 32));
    float p = (c < 17) ? __expf(logit - mm) : 0.f;
    float ssum = p;
#pragma unroll
    for (int off = 1; off < 32; off <<= 1) ssum += __shfl_xor(ssum, off, 32);
    if (c < 17 && jsub == 0) out[(size_t)node * 17 + c] = logit - mm - logf(ssum);
}

extern "C" void kernel_launch(void* const* d_in, const int* in_sizes, int n_in,
                              void* d_out, int out_size, void* d_ws, size_t ws_size,
                              hipStream_t stream)
{
    const float* x      = (const float*)d_in[0];
    const int*   ei     = (const int*)d_in[1];
    const float* W1     = (const float*)d_in[2];
    const float* asrc1w = (const float*)d_in[3];
    const float* adst1w = (const float*)d_in[4];
    const float* b1     = (const float*)d_in[5];
    const float* W2     = (const float*)d_in[6];
    const float* asrc2w = (const float*)d_in[7];
    const float* adst2w = (const float*)d_in[8];
    const float* b2     = (const float*)d_in[9];
    float* out = (float*)d_out;

    const int N = in_sizes[0] / 64;
    const int E = in_sizes[1] / 2;
    const int Etot = N + E;

    // workspace layout
    float* ws = (float*)d_ws;
    size_t o = 0;
    bf16*  y      = (bf16*)(ws + o); o += (size_t)N * 256;   // N*512 bf16
    float* wboth  = ws + o; o += 1024;
    unsigned short* W1f = (unsigned short*)(ws + o); o += 64 * 512 / 2;  // 32768 halves
    unsigned short* W2f = (unsigned short*)(ws + o); o += 32 * 512 / 2;  // 16384 bf16
    float* asrc1  = ws + o; o += (size_t)N * 8;
    float* adst1  = ws + o; o += (size_t)N * 8;
    float* aE1    = ws + o; o += (size_t)Etot * 8;
    float* h2     = ws + o; o += (size_t)N * 17;
    float* asrc2  = ws + o; o += (size_t)N;
    float* adst2  = ws + o; o += (size_t)N;
    int* deg      = (int*)(ws + o); o += (size_t)N;
    int* cur      = (int*)(ws + o); o += (size_t)N;
    int* rs       = (int*)(ws + o); o += (size_t)N + 1;
    int* csr_src  = (int*)(ws + o); o += (size_t)Etot;

    hipMemsetAsync(deg, 0, (size_t)N * 4, stream);
    hipMemsetAsync(cur, 0, (size_t)N * 4, stream);

    // CSR build
    {
        int blk = 256, g = (Etot + blk - 1) / blk;
        k_hist<<<g, blk, 0, stream>>>(ei, E, Etot, deg);
        k_scan<<<1, 1024, 0, stream>>>(deg, rs, N);
        k_fill<<<g, blk, 0, stream>>>(ei, E, Etot, rs, cur, csr_src);
    }

    // layer 1
    k_prew<<<1, 512, 0, stream>>>(W1, asrc1w, adst1w, wboth);
    k_packw1f<<<128, 256, 0, stream>>>(W1, W1f);
    k_packw2<<<64, 256, 0, stream>>>(W2, asrc2w, adst2w, W2f);
    k_alpha1n<<<(N + 15) / 16, 256, 0, stream>>>(x, wboth, asrc1, adst1, N);
    k_sm1<<<(N + 3) / 4, 256, 0, stream>>>(rs, csr_src, asrc1, adst1, aE1, N);
    k_agg_gemm1<<<(N + NPB - 1) / NPB, 512, 0, stream>>>(rs, csr_src, aE1, x, W1f, b1, y, N);

    // layer 2
    k_gemm2<<<(N + 127) / 128, 512, 0, stream>>>(y, W2f, h2, asrc2, adst2, N);
    k_out<<<(N + 3) / 4, 256, 0, stream>>>(rs, csr_src, asrc2, adst2, h2, b2, out, N);
}